// Round 7
// baseline (5146.158 us; speedup 1.0000x reference)
//
#include <hip/hip_runtime.h>
#include <stdint.h>

typedef unsigned short u16;
typedef unsigned int   u32;

typedef short bf16x8 __attribute__((ext_vector_type(8)));   // 8 bf16 in 4 VGPRs
typedef float f32x4  __attribute__((ext_vector_type(4)));

#define NROWS  2048
#define HID    256
#define BATCH  8
#define NSTEPS 10
#define MTILE  16            // rows per workgroup
#define NWGS   (NROWS/MTILE) // 128
#define THREADS 1024         // 16 waves

// ---------- helpers ----------
__device__ __forceinline__ u16 f2bf(float f) {
    union { float f; u32 u; } v; v.f = f;
    u32 r = (v.u + 0x7FFFu + ((v.u >> 16) & 1u)) >> 16;   // RNE
    return (u16)r;
}
__device__ __forceinline__ float sigm(float x) {
    return 1.0f / (1.0f + __expf(-x));
}
__device__ __forceinline__ float ftanh(float x) {
    x = fminf(fmaxf(x, -15.0f), 15.0f);
    float a = __expf(2.0f * x);
    return (a - 1.0f) / (a + 1.0f);
}
__device__ __forceinline__ f32x4 mfma16(bf16x8 a, bf16x8 b, f32x4 c) {
    return __builtin_amdgcn_mfma_f32_16x16x32_bf16(a, b, c, 0, 0, 0);
}
// async global->LDS DMA, 16B per lane; LDS dest is wave-uniform base + lane*16
__device__ __forceinline__ void gload16(const u16* g, u16* l) {
    __builtin_amdgcn_global_load_lds(
        (const __attribute__((address_space(1))) void*)g,
        (__attribute__((address_space(3))) void*)l,
        16, 0, 0);
}
// barrier that does NOT drain vmcnt: LDS visibility via lgkmcnt(0) only.
__device__ __forceinline__ void barrier_lgkm() {
    asm volatile("s_waitcnt lgkmcnt(0)" ::: "memory");
    __builtin_amdgcn_s_barrier();
    asm volatile("" ::: "memory");
}

// ---------- setup kernels (unchanged, validated) ----------
__global__ __launch_bounds__(256) void stode_wz(const float* __restrict__ Wf,
                                                const float* __restrict__ Ws2,
                                                float* __restrict__ Wz) {
    int a = blockIdx.x;
    int b = threadIdx.x;
    const float* wf2 = Wf + a * 512 + 256;
    float acc = 0.0f;
    for (int c = 0; c < 256; ++c) acc += wf2[c] * Ws2[c * 256 + b];
    Wz[a * 256 + b] = acc;
}
__global__ __launch_bounds__(256) void stode_biasf(const float* __restrict__ Wf,
                                                   const float* __restrict__ Ws2b,
                                                   const float* __restrict__ Wfb,
                                                   float* __restrict__ biasf) {
    int a = threadIdx.x;
    const float* wf2 = Wf + a * 512 + 256;
    float acc = Wfb[a];
    for (int c = 0; c < 256; ++c) acc += wf2[c] * Ws2b[c];
    biasf[a] = acc;
}
__global__ __launch_bounds__(256) void stode_pack(const float* __restrict__ Wg,
                                                  const float* __restrict__ Ws1,
                                                  const float* __restrict__ Wc,
                                                  const float* __restrict__ Wz,
                                                  const float* __restrict__ Wf,
                                                  u16* __restrict__ P1,
                                                  u16* __restrict__ P2,
                                                  u16* __restrict__ P3) {
    int i = blockIdx.x * 256 + threadIdx.x;
    const int NP1 = 48 * 8 * 64 * 8;
    const int NP2 = 32 * 8 * 64 * 8;
    int region, local;
    if (i < NP1)            { region = 0; local = i; }
    else if (i < NP1 + NP2) { region = 1; local = i - NP1; }
    else                    { region = 2; local = i - NP1 - NP2; }
    int j    = local & 7;
    int lane = (local >> 3) & 63;
    int kt   = (local >> 9) & 7;
    int ct   = local >> 12;
    int k = kt * 32 + (lane >> 4) * 8 + j;
    int c = lane & 15;
    if (region == 0) {
        float v = (ct < 32) ? Wg[(16 * ct + c) * 256 + k]
                            : Ws1[(16 * (ct - 32) + c) * 256 + k];
        P1[local] = f2bf(v);
    } else if (region == 1) {
        float v = (ct < 16) ? Wc[(16 * ct + c) * 256 + k]
                            : Wz[(16 * (ct - 16) + c) * 256 + k];
        P2[local] = f2bf(v);
    } else {
        float v = Wf[(16 * ct + c) * 512 + k];
        P3[local] = f2bf(v);
    }
}

// ---------- main persistent integrator ----------
// LDS (bytes): 3 rotating 8KB activation slots @0/@8192/@16384,
// then 16 per-wave private weight rings of 8KB (2 x 4KB slots) @24576. Total 152 KB.
#define SLOT0 0
#define SLOT1 8192
#define SLOT2 16384
#define RINGB 24576

__global__
__attribute__((amdgpu_flat_work_group_size(1024, 1024)))
__attribute__((amdgpu_waves_per_eu(4, 4)))
void stode_main(
    const float* __restrict__ h0, const float* __restrict__ tspans,
    const float* __restrict__ Wg_b, const float* __restrict__ Wc_b,
    const float* __restrict__ Wt,   const float* __restrict__ Ws1_b,
    const u16* __restrict__ P1p, const u16* __restrict__ P2p, const u16* __restrict__ P3p,
    const float* __restrict__ biasf, float* __restrict__ out)
{
    __shared__ __align__(1024) u16 SH[77824];   // 155648 bytes
    char* shb = (char*)SH;

    const int tid = threadIdx.x;
    const int wv  = tid >> 6;    // 0..15 : wave owns ct = wv (cols 16*wv..16*wv+15)
    const int ln  = tid & 63;
    const int lr  = ln & 15;
    const int lg  = ln >> 4;
    const int wg  = blockIdx.x;
    const float third = 1.0f / 3.0f;

    // per-wave private ring: two 4KB chunk slots
    char* ring0 = shb + RINGB + wv * 8192;
    char* ring1 = ring0 + 4096;

    // issue one 4-frag (4KB) weight chunk into a ring slot via async DMA
    auto dma4 = [&](const u16* __restrict__ P, int ct, int ktH, char* ring) {
        const u16* g = P + (ct * 8 + ktH * 4) * 512 + ln * 8;
        u16* l = (u16*)ring;
        #pragma unroll
        for (int f = 0; f < 4; ++f)
            gload16(g + f * 512, l + f * 512);
    };
    // consume a ring chunk: counted vmcnt (chunk is 2-older than in-flight tail),
    // 4 x ds_read_b128 -> 4 MFMA
    auto consume = [&](f32x4& acc, const bf16x8 (&af)[4], const char* ring) {
        asm volatile("s_waitcnt vmcnt(4)" ::: "memory");
        #pragma unroll
        for (int f = 0; f < 4; ++f) {
            bf16x8 bw = *(const bf16x8*)(ring + f * 1024 + ln * 16);
            acc = mfma16(af[f], bw, acc);
        }
        __builtin_amdgcn_sched_barrier(0);
    };

    // A-frag read bases: addr(k) = (k even ? tbE : tbO) + xb + k*64 (reproduces XOR swizzle)
    const int base0 = lr * 512 + ((lg * 16) ^ ((lr & 3) << 4));
    const int flp   = (lr & 4) ? 64 : 0;
    const int tbE   = base0 + flp;
    const int tbO   = base0 - flp;

    auto ldAF = [&](bf16x8 (&af)[4], int xb, int ktH) {
        #pragma unroll
        for (int kk = 0; kk < 4; ++kk) {
            int k = 4 * ktH + kk;
            af[kk] = *(const bf16x8*)(shb + ((k & 1) ? tbO : tbE) + xb + k * 64);
        }
    };
    auto st16 = [&](int xb, int row, int col, u16 v) {
        int byte = (xb + row * 512 + col * 2) ^ ((row & 7) << 4);
        *(u16*)(shb + byte) = v;
    };

    // ---- prologue: prime the ring (Z0 -> slotA, R0 -> slotB) ----
    dma4(P1p,      wv, 0, ring0);
    dma4(P1p, 16 + wv, 0, ring1);

    // biases / Wt : col = 16*wv + lr
    const int colb = 16 * wv + lr;
    float bz  = Wg_b[colb];
    float br  = Wg_b[256 + colb];
    float bs1 = Ws1_b[colb];
    float bc  = Wc_b[colb];
    float bfv = biasf[colb];
    float wtv = Wt[colb];

    // state at C/D positions: row = 4*lg + r, col = 16*wv + lr
    float y[4], kA[4], kB[4], zreg[4];
    #pragma unroll
    for (int r = 0; r < 4; ++r)
        y[r] = h0[(wg * MTILE + 4 * lg + r) * 256 + colb];

    float dt = 0.0f;

    // E recomputation (bit-identical per RK stage)
    auto calcE = [&](float (&Ev)[4], int RK) {
        if (RK == 1) {
            #pragma unroll
            for (int r = 0; r < 4; ++r) Ev[r] = y[r];
        } else if (RK == 2) {
            float c = dt * third;
            #pragma unroll
            for (int r = 0; r < 4; ++r) Ev[r] = y[r] + c * kA[r];
        } else if (RK == 3) {
            #pragma unroll
            for (int r = 0; r < 4; ++r) Ev[r] = y[r] + dt * (kB[r] - third * kA[r]);
        } else {
            #pragma unroll
            for (int r = 0; r < 4; ++r) Ev[r] = y[r] + dt * kB[r];
        }
    };

    // rotating activation slots
    int bE = SLOT0, bRE = SLOT1, bTS = SLOT2;

    auto EVAL = [&](float te, int RK) {
        // stage X_E = bf16(E)
        {
            float Ev[4]; calcE(Ev, RK);
            #pragma unroll
            for (int r = 0; r < 4; ++r)
                st16(bE, 4 * lg + r, colb, f2bf(Ev[r]));
        }
        barrier_lgkm();   // B1 (DMA stays in flight)

        // ---- P1: Z, R, S (all streamed through ring) ----
        f32x4 aZ = {0.f, 0.f, 0.f, 0.f};
        f32x4 aR = {0.f, 0.f, 0.f, 0.f};
        f32x4 aS = {0.f, 0.f, 0.f, 0.f};
        bf16x8 af[4];
        // ktH0 : consume Z0(A), R0(B), S0(A)
        ldAF(af, bE, 0);
        consume(aZ, af, ring0); dma4(P1p, 32 + wv, 0, ring0);   // issue S0
        consume(aR, af, ring1); dma4(P1p,      wv, 1, ring1);   // issue Z1
        consume(aS, af, ring0); dma4(P1p, 16 + wv, 1, ring0);   // issue R1
        // ktH1 : consume Z1(B), R1(A), S1(B)
        ldAF(af, bE, 1);
        consume(aZ, af, ring1); dma4(P1p, 32 + wv, 1, ring1);   // issue S1
        consume(aR, af, ring0); dma4(P2p,      wv, 0, ring0);   // issue C0
        consume(aS, af, ring1); dma4(P2p,      wv, 1, ring1);   // issue C1

        // epilogue-1: z,r in regs; write r*E and tanh(S1) tiles
        {
            float Ev[4]; calcE(Ev, RK);
            #pragma unroll
            for (int r = 0; r < 4; ++r) {
                zreg[r]  = sigm(aZ[r] + bz);
                float rr = sigm(aR[r] + br);
                float s  = ftanh(aS[r] + bs1);
                int row = 4 * lg + r;
                st16(bTS, row, colb, f2bf(s));
                st16(bRE, row, colb, f2bf(rr * Ev[r]));
            }
        }
        barrier_lgkm();   // B2

        // ---- P2a: C = (r*E)@Wc^T ----
        f32x4 aC = {0.f, 0.f, 0.f, 0.f};
        ldAF(af, bRE, 0);
        consume(aC, af, ring0); dma4(P2p, 16 + wv, 0, ring0);   // issue T0
        ldAF(af, bRE, 1);
        consume(aC, af, ring1); dma4(P2p, 16 + wv, 1, ring1);   // issue T1

        // ---- P2b: T1 = tanh(S1)@Wz^T ----
        f32x4 aT = {0.f, 0.f, 0.f, 0.f};
        ldAF(af, bTS, 0);
        consume(aT, af, ring0); dma4(P3p, wv, 0, ring0);        // issue F0
        ldAF(af, bTS, 1);
        consume(aT, af, ring1); dma4(P3p, wv, 1, ring1);        // issue F1

        // epilogue-2: dh_temp -> X_E slot (all waves passed B2, P1 reads done)
        {
            float tm = ftanh(te * wtv);
            float Ev[4]; calcE(Ev, RK);
            #pragma unroll
            for (int r = 0; r < 4; ++r) {
                float ht = ftanh(aC[r] + bc) + tm;
                float dh = (1.0f - zreg[r]) * (ht - Ev[r]);
                st16(bE, 4 * lg + r, colb, f2bf(dh));
            }
        }
        barrier_lgkm();   // B3

        // ---- P3: F = dh_temp@Wf1^T ----
        f32x4 aF = {0.f, 0.f, 0.f, 0.f};
        ldAF(af, bE, 0);
        consume(aF, af, ring0); dma4(P1p,      wv, 0, ring0);   // issue Z0 (next eval)
        ldAF(af, bE, 1);
        consume(aF, af, ring1); dma4(P1p, 16 + wv, 0, ring1);   // issue R0 (next eval)

        // epilogue-3: kv + RK fold (rounding order identical to reference)
        if (RK == 1) {
            #pragma unroll
            for (int r = 0; r < 4; ++r)
                kA[r] = ftanh(aF[r] + aT[r] + bfv);
        } else if (RK == 2) {
            #pragma unroll
            for (int r = 0; r < 4; ++r)
                kB[r] = ftanh(aF[r] + aT[r] + bfv);
        } else if (RK == 3) {
            #pragma unroll
            for (int r = 0; r < 4; ++r) {
                float v = ftanh(aF[r] + aT[r] + bfv);
                float a = kA[r], b = kB[r];
                kA[r] = a + 3.0f * (b + v);   // k1 + 3*(k2+k3)
                kB[r] = (a - b) + v;          // (k1-k2)+k3
            }
        } else {
            #pragma unroll
            for (int r = 0; r < 4; ++r) {
                float v = ftanh(aF[r] + aT[r] + bfv);
                y[r] += dt * 0.125f * (kA[r] + v);
            }
        }

        // rotate activation slots: next E -> old rE slot (WAR-safe)
        int tmp = bE; bE = bRE; bRE = bTS; bTS = tmp;
    };

    for (int b = 0; b < BATCH; ++b) {
        float t0 = tspans[2 * b], t1 = tspans[2 * b + 1];
        dt = (t1 - t0) / 10.0f;
        for (int s = 0; s < NSTEPS; ++s) {
            float tb = t0 + (float)s * dt;
            EVAL(tb, 1);
            EVAL(tb + dt * third, 2);
            EVAL(tb + dt * 2.0f * third, 3);
            EVAL(tb + dt, 4);
        }
        #pragma unroll
        for (int r = 0; r < 4; ++r) {
            int row = wg * MTILE + 4 * lg + r;
            out[(b * NROWS + row) * 256 + colb] = y[r];
        }
    }
}

extern "C" void kernel_launch(void* const* d_in, const int* in_sizes, int n_in,
                              void* d_out, int out_size, void* d_ws, size_t ws_size,
                              hipStream_t stream) {
    (void)in_sizes; (void)n_in; (void)out_size; (void)ws_size;
    const float* h0    = (const float*)d_in[0];
    const float* ts    = (const float*)d_in[1];
    // d_in[2] = adj_matrices : unused (spectral_reg is None)
    const float* Wg_w  = (const float*)d_in[3];
    const float* Wg_b  = (const float*)d_in[4];
    const float* Wc_w  = (const float*)d_in[5];
    const float* Wc_b  = (const float*)d_in[6];
    const float* Wt_w  = (const float*)d_in[7];
    const float* Ws1_w = (const float*)d_in[8];
    const float* Ws1_b = (const float*)d_in[9];
    const float* Ws2_w = (const float*)d_in[10];
    const float* Ws2_b = (const float*)d_in[11];
    const float* Wf_w  = (const float*)d_in[12];
    const float* Wf_b  = (const float*)d_in[13];

    char* ws = (char*)d_ws;
    u16*   P1    = (u16*)(ws);              // 393216 B
    u16*   P2    = (u16*)(ws + 393216);     // 262144 B
    u16*   P3    = (u16*)(ws + 655360);     // 131072 B
    float* Wz    = (float*)(ws + 786432);   // 262144 B
    float* biasf = (float*)(ws + 1048576);  //   1024 B

    hipLaunchKernelGGL(stode_wz,    dim3(256),  dim3(256), 0, stream, Wf_w, Ws2_w, Wz);
    hipLaunchKernelGGL(stode_biasf, dim3(1),    dim3(256), 0, stream, Wf_w, Ws2_b, Wf_b, biasf);
    hipLaunchKernelGGL(stode_pack,  dim3(1536), dim3(256), 0, stream, Wg_w, Ws1_w, Wc_w, Wz, Wf_w, P1, P2, P3);
    hipLaunchKernelGGL(stode_main,  dim3(NWGS), dim3(THREADS), 0, stream,
                       h0, ts, Wg_b, Wc_b, Wt_w, Ws1_b, P1, P2, P3, biasf, (float*)d_out);
}